// Round 2
// baseline (1127.537 us; speedup 1.0000x reference)
//
#include <hip/hip_runtime.h>
#include <hip/hip_bf16.h>
#include <math.h>

// Model constants: V=32000, D=1024, H=16, L=2, S=2048, W=256
#define SEQ    2048
#define DMODEL 1024
#define NHEAD  16
#define HDIM   64
#define NLAYER 2
#define VOCAB  32000
#define HALFW  128   // W//2

typedef float  f32x4  __attribute__((ext_vector_type(4)));
typedef short  s16x8  __attribute__((ext_vector_type(8)));

// ---------- helpers ----------
__device__ __forceinline__ unsigned bf16_rne(float x) {
    unsigned b = __builtin_bit_cast(unsigned, x);
    return (b + 0x7FFFu + ((b >> 16) & 1u)) >> 16;
}
__device__ __forceinline__ unsigned pack2(float lo, float hi) {
    return bf16_rne(lo) | (bf16_rne(hi) << 16);
}
__device__ __forceinline__ void gl_lds16(const void* g, void* l) {
    __builtin_amdgcn_global_load_lds(
        (const __attribute__((address_space(1))) unsigned*)g,
        (__attribute__((address_space(3))) unsigned*)l, 16, 0, 0);
}

// ---------- embedding ----------
__global__ __launch_bounds__(256) void embed_kernel(
    const int* __restrict__ ids, const float* __restrict__ emb,
    const float* __restrict__ pos, float* __restrict__ X)
{
    const int s = blockIdx.x;
    const int t = threadIdx.x;
    const int id = ids[s];
    f32x4 e = *(const f32x4*)(emb + (size_t)id * DMODEL + t * 4);
    f32x4 p = *(const f32x4*)(pos + (size_t)s  * DMODEL + t * 4);
    *(f32x4*)(X + (size_t)s * DMODEL + t * 4) = e + p;
}

// ---------- f32 -> bf16 elementwise (8 elems/thread) ----------
__global__ __launch_bounds__(256) void convert_bf16_kernel(
    const float* __restrict__ X, unsigned short* __restrict__ Y)
{
    const size_t i = (size_t)blockIdx.x * 256 + threadIdx.x;
    f32x4 a = *(const f32x4*)(X + i * 8);
    f32x4 b = *(const f32x4*)(X + i * 8 + 4);
    uint4 u = make_uint4(pack2(a.x, a.y), pack2(a.z, a.w),
                         pack2(b.x, b.y), pack2(b.z, b.w));
    *(uint4*)(Y + i * 8) = u;
}

// ---------- W[K,N] f32 -> Wt[N,K] bf16, 64x64 tiles ----------
__global__ __launch_bounds__(256) void transpose_bf16_kernel(
    const float* __restrict__ W, unsigned short* __restrict__ Wt, int K, int N)
{
    __shared__ unsigned short tile[64][65];
    const int k0 = blockIdx.x * 64;
    const int n0 = blockIdx.y * 64;
    const int t = threadIdx.x;
    const int tr = t >> 6;     // 0..3
    const int tc = t & 63;
    #pragma unroll
    for (int i = 0; i < 16; ++i) {
        int r = i * 4 + tr;
        tile[r][tc] = (unsigned short)bf16_rne(W[(size_t)(k0 + r) * N + n0 + tc]);
    }
    __syncthreads();
    #pragma unroll
    for (int i = 0; i < 16; ++i) {
        int r = i * 4 + tr;
        Wt[(size_t)(n0 + r) * K + k0 + tc] = tile[tc][r];
    }
}

// ---------- pack 3 bias vectors [D] into [3D] ----------
__global__ __launch_bounds__(256) void pack3_kernel(
    const float* __restrict__ a, const float* __restrict__ b,
    const float* __restrict__ c, float* __restrict__ out)
{
    const int i = blockIdx.x * 256 + threadIdx.x;   // 0..3071
    float v = (i < 1024) ? a[i] : (i < 2048 ? b[i - 1024] : c[i - 2048]);
    out[i] = v;
}

// ---------- layernorm, bf16 output ----------
__global__ __launch_bounds__(256) void ln_bf16_kernel(
    const float* __restrict__ X, const float* __restrict__ G,
    const float* __restrict__ Bb, unsigned short* __restrict__ Y)
{
    const int row = blockIdx.x;
    const int t = threadIdx.x;
    const float* xp = X + (size_t)row * DMODEL;
    f32x4 v = *(const f32x4*)(xp + t * 4);
    float s1 = v.x + v.y + v.z + v.w;
    float s2 = v.x * v.x + v.y * v.y + v.z * v.z + v.w * v.w;
    #pragma unroll
    for (int off = 32; off; off >>= 1) {
        s1 += __shfl_down(s1, off);
        s2 += __shfl_down(s2, off);
    }
    __shared__ float red[8];
    const int wave = t >> 6, lane = t & 63;
    if (lane == 0) { red[wave] = s1; red[wave + 4] = s2; }
    __syncthreads();
    s1 = red[0] + red[1] + red[2] + red[3];
    s2 = red[4] + red[5] + red[6] + red[7];
    const float mu  = s1 * (1.0f / DMODEL);
    const float var = s2 * (1.0f / DMODEL) - mu * mu;
    const float rs  = rsqrtf(var + 1e-5f);
    f32x4 g = *(const f32x4*)(G + t * 4);
    f32x4 b = *(const f32x4*)(Bb + t * 4);
    float y0 = (v.x - mu) * rs * g.x + b.x;
    float y1 = (v.y - mu) * rs * g.y + b.y;
    float y2 = (v.z - mu) * rs * g.z + b.z;
    float y3 = (v.w - mu) * rs * g.w + b.w;
    *(uint2*)(Y + (size_t)row * DMODEL + t * 4) = make_uint2(pack2(y0, y1), pack2(y2, y3));
}

// ---------- GEMM: C[M,N] = A[M,K](bf16) * Bt[N,K](bf16) ----------
// BN=128, BK=32. 256 threads = 4 waves. global_load_lds staging (LDS dest
// linear), k-slot XOR-swizzled on the GLOBAL source + the SAME involution on
// the LDS fragment read (rule #21) -> conflict-free ds_read_b128.
// SWZ: bijective XCD chunk swizzle of the flat block id (grid must be %8==0).
template<int BM, int GELU, int OUT_BF16, int SWZ>
__global__ __launch_bounds__(256) void gemm_bf16(
    const unsigned short* __restrict__ A,
    const unsigned short* __restrict__ Bt,
    const float* __restrict__ bias, const float* __restrict__ resid,
    float* __restrict__ C, unsigned short* __restrict__ Cb,
    int M, int N, int K)
{
    constexpr int MW = BM / 64;      // waves along M
    constexpr int NW = 4 / MW;       // waves along N
    constexpr int WN = 128 / NW;     // wave tile N
    constexpr int MI = 4;            // wave tile M = 64 -> 4 frags
    constexpr int NI = WN / 16;

    __shared__ unsigned short As[BM * 32];
    __shared__ unsigned short Bs[128 * 32];

    const int t = threadIdx.x;
    const int wave = t >> 6, lane = t & 63;

    int bx = blockIdx.x, by = blockIdx.y;
    if (SWZ) {
        const int gx = gridDim.x;
        const int nwg = gx * gridDim.y;
        const int flat = by * gx + bx;
        const int chunk = nwg >> 3;
        const int nf = (flat & 7) * chunk + (flat >> 3);
        bx = nf % gx;  by = nf / gx;
    }
    const int m0 = bx * BM;
    const int n0 = by * 128;

    const int wm = (wave % MW) * 64;
    const int wn = (wave / MW) * WN;
    const int lrow = lane & 15, quad = lane >> 4;

    const int ldsub = lane >> 2;          // row within 16-row chunk
    // swizzled k-offset: LDS slot (lane&3) of row (lane>>2) holds global
    // k-chunk (lane&3) ^ ((lane>>3)&3)  [involution; undone on read]
    const int kofs  = (((lane & 3) ^ ((lane >> 3) & 3)) * 8);
    const int rsw   = (lrow >> 1) & 3;    // read-side slot swizzle

    f32x4 acc[MI][NI] = {};

    const unsigned short* Ap = A + (size_t)m0 * K + kofs;
    const unsigned short* Bp = Bt + (size_t)n0 * K + kofs;

    for (int k0 = 0; k0 < K; k0 += 32) {
        __syncthreads();
        #pragma unroll
        for (int i = 0; i < MW; ++i) {
            const int r = i * 4 + wave;
            gl_lds16(Ap + (size_t)(r * 16 + ldsub) * K + k0, (char*)As + r * 1024);
        }
        #pragma unroll
        for (int i = 0; i < 2; ++i) {
            const int r = i * 4 + wave;
            gl_lds16(Bp + (size_t)(r * 16 + ldsub) * K + k0, (char*)Bs + r * 1024);
        }
        __syncthreads();

        s16x8 af[MI], bfr[NI];
        #pragma unroll
        for (int i = 0; i < MI; ++i)
            af[i] = *(const s16x8*)(As + (wm + i * 16 + lrow) * 32 + ((quad ^ rsw) * 8));
        #pragma unroll
        for (int j = 0; j < NI; ++j)
            bfr[j] = *(const s16x8*)(Bs + (wn + j * 16 + lrow) * 32 + ((quad ^ rsw) * 8));
        #pragma unroll
        for (int i = 0; i < MI; ++i)
            #pragma unroll
            for (int j = 0; j < NI; ++j)
                acc[i][j] = __builtin_amdgcn_mfma_f32_16x16x32_bf16(af[i], bfr[j], acc[i][j], 0, 0, 0);
    }

    #pragma unroll
    for (int j = 0; j < NI; ++j) {
        const int col = n0 + wn + j * 16 + lrow;
        const float bv = bias ? bias[col] : 0.0f;
        #pragma unroll
        for (int i = 0; i < MI; ++i) {
            #pragma unroll
            for (int r = 0; r < 4; ++r) {
                const int row = m0 + wm + i * 16 + quad * 4 + r;
                float vv = acc[i][j][r] + bv;
                if (GELU) vv = 0.5f * vv * (1.0f + erff(vv * 0.70710678118f));
                const size_t off = (size_t)row * N + col;
                if (OUT_BF16) {
                    Cb[off] = (unsigned short)bf16_rne(vv);
                } else {
                    if (resid) vv += resid[off];
                    C[off] = vv;
                }
            }
        }
    }
}

// ---------- MFMA band attention ----------
__global__ __launch_bounds__(256) void attn_mfma_kernel(
    const unsigned short* __restrict__ QKV, unsigned short* __restrict__ O)
{
    constexpr int LDK = 72;   // K/V row stride in bf16 elems (144 B, conflict-free)
    constexpr int LDP = 40;   // P row stride (80 B)
    __shared__ unsigned short Ks[32 * LDK];
    __shared__ unsigned short Vs[32 * LDK];
    __shared__ unsigned short Pl[4][16 * LDP];

    const int t    = threadIdx.x;
    const int wave = t >> 6;
    const int lane = t & 63;
    const int quad = lane >> 4;
    const int c    = lane & 15;
    const int h    = blockIdx.y;
    const int q0   = blockIdx.x * 64;
    const int qw   = q0 + wave * 16;

    const int srow = t >> 3;
    const int scol = (t & 7) * 8;

    const unsigned short* qrow = QKV + (size_t)(qw + c) * 3072 + h * HDIM;
    const s16x8 qf0 = *(const s16x8*)(qrow + quad * 8);
    const s16x8 qf1 = *(const s16x8*)(qrow + 32 + quad * 8);

    float m = -1e30f, lsum = 0.0f;
    f32x4 oacc[4] = {};
    unsigned short* pb = &Pl[wave][0];

    for (int kb = 0; kb < 10; ++kb) {
        const int kstart = q0 - HALFW + kb * 32;
        __syncthreads();
        {
            const int kc = min(max(kstart + srow, 0), SEQ - 1);
            const unsigned short* kr = QKV + (size_t)kc * 3072 + DMODEL + h * HDIM + scol;
            const uint4 kvv = *(const uint4*)kr;
            const uint4 vvv = *(const uint4*)(kr + DMODEL);
            *(uint4*)(Ks + srow * LDK + scol) = kvv;
            *(uint4*)(Vs + srow * LDK + scol) = vvv;
        }
        __syncthreads();

        if (kstart > qw + 15 + HALFW || kstart + 31 < qw - HALFW ||
            kstart + 31 < 0 || kstart >= SEQ)
            continue;

        f32x4 st0 = {0.f, 0.f, 0.f, 0.f}, st1 = {0.f, 0.f, 0.f, 0.f};
        {
            const s16x8 ka00 = *(const s16x8*)(Ks + c * LDK + quad * 8);
            const s16x8 ka01 = *(const s16x8*)(Ks + c * LDK + 32 + quad * 8);
            const s16x8 ka10 = *(const s16x8*)(Ks + (16 + c) * LDK + quad * 8);
            const s16x8 ka11 = *(const s16x8*)(Ks + (16 + c) * LDK + 32 + quad * 8);
            st0 = __builtin_amdgcn_mfma_f32_16x16x32_bf16(ka00, qf0, st0, 0, 0, 0);
            st0 = __builtin_amdgcn_mfma_f32_16x16x32_bf16(ka01, qf1, st0, 0, 0, 0);
            st1 = __builtin_amdgcn_mfma_f32_16x16x32_bf16(ka10, qf0, st1, 0, 0, 0);
            st1 = __builtin_amdgcn_mfma_f32_16x16x32_bf16(ka11, qf1, st1, 0, 0, 0);
        }

        float sv[8];
        #pragma unroll
        for (int j = 0; j < 8; ++j) {
            const int half = j >> 2, r = j & 3;
            const int key = kstart + half * 16 + quad * 4 + r;
            const int d = key - (qw + c);
            const bool valid = (key >= 0) && (key < SEQ) && (d <= HALFW) && (d >= -HALFW);
            const float s = (half ? st1[r] : st0[r]) * 0.125f;
            sv[j] = valid ? s : -1e30f;
        }
        float tmax = sv[0];
        #pragma unroll
        for (int j = 1; j < 8; ++j) tmax = fmaxf(tmax, sv[j]);
        tmax = fmaxf(tmax, __shfl_xor(tmax, 16));
        tmax = fmaxf(tmax, __shfl_xor(tmax, 32));
        const float mnew = fmaxf(m, tmax);
        const float alpha = __expf(m - mnew);
        m = mnew;

        float p[8], psum = 0.0f;
        #pragma unroll
        for (int j = 0; j < 8; ++j) {
            p[j] = (sv[j] > -1e29f) ? __expf(sv[j] - mnew) : 0.0f;
            psum += p[j];
        }
        psum += __shfl_xor(psum, 16);
        psum += __shfl_xor(psum, 32);
        lsum = lsum * alpha + psum;

        #pragma unroll
        for (int j = 0; j < 8; ++j) {
            const int half = j >> 2, r = j & 3;
            pb[c * LDP + half * 16 + quad * 4 + r] = (unsigned short)bf16_rne(p[j]);
        }

        #pragma unroll
        for (int r = 0; r < 4; ++r) {
            const float ar = __shfl(alpha, quad * 4 + r);
            oacc[0][r] *= ar; oacc[1][r] *= ar; oacc[2][r] *= ar; oacc[3][r] *= ar;
        }

        asm volatile("" ::: "memory");
        const s16x8 pa = *(const s16x8*)(pb + c * LDP + quad * 8);

        #pragma unroll
        for (int dt = 0; dt < 4; ++dt) {
            s16x8 vb;
            #pragma unroll
            for (int i = 0; i < 8; ++i)
                vb[i] = (short)Vs[(quad * 8 + i) * LDK + dt * 16 + c];
            oacc[dt] = __builtin_amdgcn_mfma_f32_16x16x32_bf16(pa, vb, oacc[dt], 0, 0, 0);
        }
    }

    #pragma unroll
    for (int r = 0; r < 4; ++r) {
        const float li = 1.0f / __shfl(lsum, quad * 4 + r);
        unsigned short* op = O + (size_t)(qw + quad * 4 + r) * DMODEL + h * HDIM + c;
        op[0]  = (unsigned short)bf16_rne(oacc[0][r] * li);
        op[16] = (unsigned short)bf16_rne(oacc[1][r] * li);
        op[32] = (unsigned short)bf16_rne(oacc[2][r] * li);
        op[48] = (unsigned short)bf16_rne(oacc[3][r] * li);
    }
}

// ---------- launch ----------
extern "C" void kernel_launch(void* const* d_in, const int* in_sizes, int n_in,
                              void* d_out, int out_size, void* d_ws, size_t ws_size,
                              hipStream_t stream)
{
    const int*   ids  = (const int*)d_in[0];
    const float* emb  = (const float*)d_in[1];
    const float* pos  = (const float*)d_in[2];
    const float* wq   = (const float*)d_in[3];
    const float* bq   = (const float*)d_in[4];
    const float* wk   = (const float*)d_in[5];
    const float* bk   = (const float*)d_in[6];
    const float* wv   = (const float*)d_in[7];
    const float* bv   = (const float*)d_in[8];
    const float* wo   = (const float*)d_in[9];
    const float* bo   = (const float*)d_in[10];
    const float* w1   = (const float*)d_in[11];
    const float* b1   = (const float*)d_in[12];
    const float* w2   = (const float*)d_in[13];
    const float* b2   = (const float*)d_in[14];
    const float* ln1g = (const float*)d_in[15];
    const float* ln1b = (const float*)d_in[16];
    const float* ln2g = (const float*)d_in[17];
    const float* ln2b = (const float*)d_in[18];
    const float* outg = (const float*)d_in[19];
    const float* outb = (const float*)d_in[20];

    const size_t SD = (size_t)SEQ * DMODEL;       // 2M
    char* ws = (char*)d_ws;
    float*          x     = (float*)ws;           ws += SD * 4;                       // 8 MB
    unsigned short* qkvb  = (unsigned short*)ws;  ws += (size_t)SEQ * 3 * DMODEL * 2; // 12.6 MB
    unsigned short* hb    = (unsigned short*)ws;  ws += SD * 2;                       // 4 MB
    unsigned short* ob    = (unsigned short*)ws;  ws += SD * 2;                       // 4 MB
    unsigned short* mid   = (unsigned short*)ws;  ws += (size_t)SEQ * 4 * DMODEL * 2; // 16.8 MB
    unsigned short* embT  = (unsigned short*)ws;  ws += (size_t)VOCAB * DMODEL * 2;   // 65.5 MB
    unsigned short* wT    = (unsigned short*)ws;  ws += (size_t)4 * DMODEL * DMODEL * 2; // 8.4 MB
    float*          bias3 = (float*)ws;           ws += 3 * DMODEL * 4;

    const size_t DD  = (size_t)DMODEL * DMODEL;
    const size_t DD4 = (size_t)DMODEL * 4 * DMODEL;

    // emb f32 -> bf16 (layout [V,K] is already the BT layout for logits)
    convert_bf16_kernel<<<(VOCAB * DMODEL) / (256 * 8), 256, 0, stream>>>(emb, embT);

    embed_kernel<<<SEQ, 256, 0, stream>>>(ids, emb, pos, x);

    for (int l = 0; l < NLAYER; ++l) {
        ln_bf16_kernel<<<SEQ, 256, 0, stream>>>(x, ln1g + l * DMODEL, ln1b + l * DMODEL, hb);

        // QKV fused: Wt = [wq^T ; wk^T ; wv^T]  (3072 x 1024), bf16 output
        transpose_bf16_kernel<<<dim3(16, 16), 256, 0, stream>>>(wq + l * DD, wT,          DMODEL, DMODEL);
        transpose_bf16_kernel<<<dim3(16, 16), 256, 0, stream>>>(wk + l * DD, wT + DD,     DMODEL, DMODEL);
        transpose_bf16_kernel<<<dim3(16, 16), 256, 0, stream>>>(wv + l * DD, wT + 2 * DD, DMODEL, DMODEL);
        pack3_kernel<<<12, 256, 0, stream>>>(bq + l * DMODEL, bk + l * DMODEL, bv + l * DMODEL, bias3);

        gemm_bf16<128, 0, 1, 1><<<dim3(16, 24), 256, 0, stream>>>(
            hb, wT, bias3, nullptr, nullptr, qkvb, SEQ, 3 * DMODEL, DMODEL);

        attn_mfma_kernel<<<dim3(SEQ / 64, NHEAD), 256, 0, stream>>>(qkvb, ob);

        transpose_bf16_kernel<<<dim3(16, 16), 256, 0, stream>>>(wo + l * DD, wT, DMODEL, DMODEL);
        gemm_bf16<64, 0, 0, 0><<<dim3(32, 8), 256, 0, stream>>>(
            ob, wT, bo + l * DMODEL, x, x, nullptr, SEQ, DMODEL, DMODEL);

        ln_bf16_kernel<<<SEQ, 256, 0, stream>>>(x, ln2g + l * DMODEL, ln2b + l * DMODEL, hb);

        transpose_bf16_kernel<<<dim3(16, 64), 256, 0, stream>>>(w1 + l * DD4, wT, DMODEL, 4 * DMODEL);
        gemm_bf16<128, 1, 1, 1><<<dim3(16, 32), 256, 0, stream>>>(
            hb, wT, b1 + l * 4 * DMODEL, nullptr, nullptr, mid, SEQ, 4 * DMODEL, DMODEL);

        transpose_bf16_kernel<<<dim3(64, 16), 256, 0, stream>>>(w2 + l * DD4, wT, 4 * DMODEL, DMODEL);
        gemm_bf16<64, 0, 0, 0><<<dim3(32, 8), 256, 0, stream>>>(
            mid, wT, b2 + l * DMODEL, x, x, nullptr, SEQ, DMODEL, 4 * DMODEL);
    }

    ln_bf16_kernel<<<SEQ, 256, 0, stream>>>(x, outg, outb, hb);

    // logits = hb @ embT^T  -> d_out f32
    gemm_bf16<128, 0, 0, 1><<<dim3(16, VOCAB / 128), 256, 0, stream>>>(
        hb, embT, nullptr, nullptr, (float*)d_out, nullptr, SEQ, VOCAB, DMODEL);
}

// Round 5
// 1083.866 us; speedup vs baseline: 1.0403x; 1.0403x over previous
//
#include <hip/hip_runtime.h>
#include <hip/hip_bf16.h>
#include <math.h>

// Model constants: V=32000, D=1024, H=16, L=2, S=2048, W=256
#define SEQ    2048
#define DMODEL 1024
#define NHEAD  16
#define HDIM   64
#define NLAYER 2
#define VOCAB  32000
#define HALFW  128   // W//2

typedef float  f32x4  __attribute__((ext_vector_type(4)));
typedef short  s16x8  __attribute__((ext_vector_type(8)));

// ---------- helpers ----------
__device__ __forceinline__ unsigned bf16_rne(float x) {
    unsigned b = __builtin_bit_cast(unsigned, x);
    return (b + 0x7FFFu + ((b >> 16) & 1u)) >> 16;
}
__device__ __forceinline__ unsigned pack2(float lo, float hi) {
    return bf16_rne(lo) | (bf16_rne(hi) << 16);
}
__device__ __forceinline__ void gl_lds16(const void* g, void* l) {
    __builtin_amdgcn_global_load_lds(
        (const __attribute__((address_space(1))) unsigned*)g,
        (__attribute__((address_space(3))) unsigned*)l, 16, 0, 0);
}

// ---------- embedding ----------
__global__ __launch_bounds__(256) void embed_kernel(
    const int* __restrict__ ids, const float* __restrict__ emb,
    const float* __restrict__ pos, float* __restrict__ X)
{
    const int s = blockIdx.x;
    const int t = threadIdx.x;
    const int id = ids[s];
    f32x4 e = *(const f32x4*)(emb + (size_t)id * DMODEL + t * 4);
    f32x4 p = *(const f32x4*)(pos + (size_t)s  * DMODEL + t * 4);
    *(f32x4*)(X + (size_t)s * DMODEL + t * 4) = e + p;
}

// ---------- f32 -> bf16 elementwise (8 elems/thread) ----------
__global__ __launch_bounds__(256) void convert_bf16_kernel(
    const float* __restrict__ X, unsigned short* __restrict__ Y)
{
    const size_t i = (size_t)blockIdx.x * 256 + threadIdx.x;
    f32x4 a = *(const f32x4*)(X + i * 8);
    f32x4 b = *(const f32x4*)(X + i * 8 + 4);
    uint4 u = make_uint4(pack2(a.x, a.y), pack2(a.z, a.w),
                         pack2(b.x, b.y), pack2(b.z, b.w));
    *(uint4*)(Y + i * 8) = u;
}

// ---------- W[K,N] f32 -> Wt[N,K] bf16, 64x64 tiles ----------
__global__ __launch_bounds__(256) void transpose_bf16_kernel(
    const float* __restrict__ W, unsigned short* __restrict__ Wt, int K, int N)
{
    __shared__ unsigned short tile[64][65];
    const int k0 = blockIdx.x * 64;
    const int n0 = blockIdx.y * 64;
    const int t = threadIdx.x;
    const int tr = t >> 6;     // 0..3
    const int tc = t & 63;
    #pragma unroll
    for (int i = 0; i < 16; ++i) {
        int r = i * 4 + tr;
        tile[r][tc] = (unsigned short)bf16_rne(W[(size_t)(k0 + r) * N + n0 + tc]);
    }
    __syncthreads();
    #pragma unroll
    for (int i = 0; i < 16; ++i) {
        int r = i * 4 + tr;
        Wt[(size_t)(n0 + r) * K + k0 + tc] = tile[tc][r];
    }
}

// ---------- pack 3 bias vectors [D] into [3D] ----------
__global__ __launch_bounds__(256) void pack3_kernel(
    const float* __restrict__ a, const float* __restrict__ b,
    const float* __restrict__ c, float* __restrict__ out)
{
    const int i = blockIdx.x * 256 + threadIdx.x;   // 0..3071
    float v = (i < 1024) ? a[i] : (i < 2048 ? b[i - 1024] : c[i - 2048]);
    out[i] = v;
}

// ---------- layernorm, bf16 output ----------
__global__ __launch_bounds__(256) void ln_bf16_kernel(
    const float* __restrict__ X, const float* __restrict__ G,
    const float* __restrict__ Bb, unsigned short* __restrict__ Y)
{
    const int row = blockIdx.x;
    const int t = threadIdx.x;
    const float* xp = X + (size_t)row * DMODEL;
    f32x4 v = *(const f32x4*)(xp + t * 4);
    float s1 = v.x + v.y + v.z + v.w;
    float s2 = v.x * v.x + v.y * v.y + v.z * v.z + v.w * v.w;
    #pragma unroll
    for (int off = 32; off; off >>= 1) {
        s1 += __shfl_down(s1, off);
        s2 += __shfl_down(s2, off);
    }
    __shared__ float red[8];
    const int wave = t >> 6, lane = t & 63;
    if (lane == 0) { red[wave] = s1; red[wave + 4] = s2; }
    __syncthreads();
    s1 = red[0] + red[1] + red[2] + red[3];
    s2 = red[4] + red[5] + red[6] + red[7];
    const float mu  = s1 * (1.0f / DMODEL);
    const float var = s2 * (1.0f / DMODEL) - mu * mu;
    const float rs  = rsqrtf(var + 1e-5f);
    f32x4 g = *(const f32x4*)(G + t * 4);
    f32x4 b = *(const f32x4*)(Bb + t * 4);
    float y0 = (v.x - mu) * rs * g.x + b.x;
    float y1 = (v.y - mu) * rs * g.y + b.y;
    float y2 = (v.z - mu) * rs * g.z + b.z;
    float y3 = (v.w - mu) * rs * g.w + b.w;
    *(uint2*)(Y + (size_t)row * DMODEL + t * 4) = make_uint2(pack2(y0, y1), pack2(y2, y3));
}

// ---------- GEMM 128x128 (2-phase), used for per-layer GEMMs ----------
template<int BM, int GELU, int OUT_BF16, int SWZ>
__global__ __launch_bounds__(256) void gemm_bf16(
    const unsigned short* __restrict__ A,
    const unsigned short* __restrict__ Bt,
    const float* __restrict__ bias, const float* __restrict__ resid,
    float* __restrict__ C, unsigned short* __restrict__ Cb,
    int M, int N, int K)
{
    constexpr int MW = BM / 64;      // waves along M
    constexpr int NW = 4 / MW;       // waves along N
    constexpr int WN = 128 / NW;     // wave tile N
    constexpr int MI = 4;            // wave tile M = 64 -> 4 frags
    constexpr int NI = WN / 16;

    __shared__ unsigned short As[BM * 32];
    __shared__ unsigned short Bs[128 * 32];

    const int t = threadIdx.x;
    const int wave = t >> 6, lane = t & 63;

    int bx = blockIdx.x, by = blockIdx.y;
    if (SWZ) {
        const int gx = gridDim.x;
        const int nwg = gx * gridDim.y;
        const int flat = by * gx + bx;
        const int chunk = nwg >> 3;
        const int nf = (flat & 7) * chunk + (flat >> 3);
        bx = nf % gx;  by = nf / gx;
    }
    const int m0 = bx * BM;
    const int n0 = by * 128;

    const int wm = (wave % MW) * 64;
    const int wn = (wave / MW) * WN;
    const int lrow = lane & 15, quad = lane >> 4;

    const int ldsub = lane >> 2;          // row within 16-row chunk
    const int kofs  = (((lane & 3) ^ ((lane >> 3) & 3)) * 8);
    const int rsw   = (lrow >> 1) & 3;    // read-side slot swizzle

    f32x4 acc[MI][NI] = {};

    const unsigned short* Ap = A + (size_t)m0 * K + kofs;
    const unsigned short* Bp = Bt + (size_t)n0 * K + kofs;

    for (int k0 = 0; k0 < K; k0 += 32) {
        __syncthreads();
        #pragma unroll
        for (int i = 0; i < MW; ++i) {
            const int r = i * 4 + wave;
            gl_lds16(Ap + (size_t)(r * 16 + ldsub) * K + k0, (char*)As + r * 1024);
        }
        #pragma unroll
        for (int i = 0; i < 2; ++i) {
            const int r = i * 4 + wave;
            gl_lds16(Bp + (size_t)(r * 16 + ldsub) * K + k0, (char*)Bs + r * 1024);
        }
        __syncthreads();

        s16x8 af[MI], bfr[NI];
        #pragma unroll
        for (int i = 0; i < MI; ++i)
            af[i] = *(const s16x8*)(As + (wm + i * 16 + lrow) * 32 + ((quad ^ rsw) * 8));
        #pragma unroll
        for (int j = 0; j < NI; ++j)
            bfr[j] = *(const s16x8*)(Bs + (wn + j * 16 + lrow) * 32 + ((quad ^ rsw) * 8));
        #pragma unroll
        for (int i = 0; i < MI; ++i)
            #pragma unroll
            for (int j = 0; j < NI; ++j)
                acc[i][j] = __builtin_amdgcn_mfma_f32_16x16x32_bf16(af[i], bfr[j], acc[i][j], 0, 0, 0);
    }

    #pragma unroll
    for (int j = 0; j < NI; ++j) {
        const int col = n0 + wn + j * 16 + lrow;
        const float bv = bias ? bias[col] : 0.0f;
        #pragma unroll
        for (int i = 0; i < MI; ++i) {
            #pragma unroll
            for (int r = 0; r < 4; ++r) {
                const int row = m0 + wm + i * 16 + quad * 4 + r;
                float vv = acc[i][j][r] + bv;
                if (GELU) vv = 0.5f * vv * (1.0f + erff(vv * 0.70710678118f));
                const size_t off = (size_t)row * N + col;
                if (OUT_BF16) {
                    Cb[off] = (unsigned short)bf16_rne(vv);
                } else {
                    if (resid) vv += resid[off];
                    C[off] = vv;
                }
            }
        }
    }
}

// ---------- GEMM 256x256, BK=64, 8 waves, phase-interleaved pipeline --------
// C[M,N] f32 = A[M,K](bf16) * Bt[N,K](bf16).  Grid (M/256, N/256).
// Double-buffered K-tiles.  Tile top: vmcnt(0)+barrier (prev prefetch had a
// whole group of MFMA to land), THEN issue next tile's prefetch into buf^1.
// Each phase pins ds_read completion BEFORE its trailing barrier via explicit
// lgkmcnt(0) + sched_barrier(0)  (rule #18: implicit waits can sink past raw
// s_barrier -> write-after-read race on the LDS double buffer).
#define PHASE256(mib, nib)                                                     \
  {                                                                            \
    s16x8 af[4][2], bfv[2][2];                                                 \
    _Pragma("unroll") for (int mi = 0; mi < 4; ++mi)                           \
      _Pragma("unroll") for (int kk = 0; kk < 2; ++kk)                         \
        af[mi][kk] = *(const s16x8*)(Asb +                                     \
            (wr * 128 + ((mib)*4 + mi) * 16 + lrow) * 64 +                     \
            (((kk * 4 + quad) ^ r7) * 8));                                     \
    _Pragma("unroll") for (int ni = 0; ni < 2; ++ni)                           \
      _Pragma("unroll") for (int kk = 0; kk < 2; ++kk)                         \
        bfv[ni][kk] = *(const s16x8*)(Bsb +                                    \
            (wc * 64 + ((nib)*2 + ni) * 16 + lrow) * 64 +                      \
            (((kk * 4 + quad) ^ r7) * 8));                                     \
    __builtin_amdgcn_s_barrier();                                              \
    asm volatile("s_waitcnt lgkmcnt(0)" ::: "memory");                         \
    __builtin_amdgcn_sched_barrier(0);                                         \
    __builtin_amdgcn_s_setprio(1);                                             \
    _Pragma("unroll") for (int mi = 0; mi < 4; ++mi)                           \
      _Pragma("unroll") for (int ni = 0; ni < 2; ++ni)                         \
        _Pragma("unroll") for (int kk = 0; kk < 2; ++kk)                       \
          acc[(mib)*4 + mi][(nib)*2 + ni] =                                    \
              __builtin_amdgcn_mfma_f32_16x16x32_bf16(                         \
                  af[mi][kk], bfv[ni][kk], acc[(mib)*4 + mi][(nib)*2 + ni],    \
                  0, 0, 0);                                                    \
    __builtin_amdgcn_s_setprio(0);                                             \
    __builtin_amdgcn_sched_barrier(0);                                         \
    __builtin_amdgcn_s_barrier();                                              \
  }

__global__ __launch_bounds__(512) void gemm256_bf16(
    const unsigned short* __restrict__ A,
    const unsigned short* __restrict__ Bt,
    float* __restrict__ C, int M, int N, int K)
{
    __shared__ unsigned short As[2][256 * 64];   // 2 x 32 KiB
    __shared__ unsigned short Bs[2][256 * 64];   // 2 x 32 KiB  (total 128 KiB)

    const int t = threadIdx.x;
    const int wave = t >> 6, lane = t & 63;
    const int wr = wave >> 2, wc = wave & 3;        // 2M x 4N wave grid
    const int lrow = lane & 15, quad = lane >> 4;
    const int r7 = lrow & 7;

    // XCD chunk swizzle (grid.x*grid.y must be % 8 == 0)
    int bx = blockIdx.x, by = blockIdx.y;
    {
        const int gx = gridDim.x;
        const int nwg = gx * gridDim.y;
        const int flat = by * gx + bx;
        const int chunk = nwg >> 3;
        const int nf = (flat & 7) * chunk + (flat >> 3);
        bx = nf % gx;  by = nf / gx;
    }
    const int m0 = bx * 256;
    const int n0 = by * 256;

    // staging: lane fills LDS row (granule-local lane>>3), slot lane&7; the
    // global k-chunk fetched is (lane&7)^(lane>>3) [swizzle on source, LDS
    // linear — rule #21]; undone on fragment reads via ^r7.
    const int grow = lane >> 3;
    const int gchk = (lane & 7) ^ grow;
    const unsigned short* Ag = A + (size_t)(m0 + grow) * K + gchk * 8;
    const unsigned short* Bg = Bt + (size_t)(n0 + grow) * K + gchk * 8;

    f32x4 acc[8][4] = {};

    const int NT = K >> 6;   // K-tiles of 64

    // prologue: stage tile 0 -> buf 0
    #pragma unroll
    for (int i = 0; i < 4; ++i) {
        const int ga = i * 8 + wave;
        gl_lds16(Ag + (size_t)(8 * ga) * K, (char*)&As[0][0] + ga * 1024);
        gl_lds16(Bg + (size_t)(8 * ga) * K, (char*)&Bs[0][0] + ga * 1024);
    }

    int buf = 0;
    for (int kt = 0; kt < NT; ++kt) {
        // tile top: prev prefetch (this tile's data) must be fully landed for
        // ALL waves before anyone reads it.
        asm volatile("s_waitcnt vmcnt(0)" ::: "memory");
        __builtin_amdgcn_s_barrier();
        __builtin_amdgcn_sched_barrier(0);
        // issue next tile's prefetch into buf^1 (safe: all reads of buf^1
        // completed before each phase's trailing barrier of the prev group)
        if (kt + 1 < NT) {
            const size_t kof = (size_t)(kt + 1) * 64;
            #pragma unroll
            for (int i = 0; i < 4; ++i) {
                const int ga = i * 8 + wave;
                gl_lds16(Ag + (size_t)(8 * ga) * K + kof, (char*)&As[buf ^ 1][0] + ga * 1024);
                gl_lds16(Bg + (size_t)(8 * ga) * K + kof, (char*)&Bs[buf ^ 1][0] + ga * 1024);
            }
        }
        const unsigned short* Asb = &As[buf][0];
        const unsigned short* Bsb = &Bs[buf][0];
        PHASE256(0, 0)
        PHASE256(0, 1)
        PHASE256(1, 0)
        PHASE256(1, 1)
        buf ^= 1;
    }

    // epilogue: C row = m0 + wr*128 + mi*16 + quad*4 + r, col = n0 + wc*64 + ni*16 + lrow
    #pragma unroll
    for (int mi = 0; mi < 8; ++mi) {
        #pragma unroll
        for (int ni = 0; ni < 4; ++ni) {
            const int col = n0 + wc * 64 + ni * 16 + lrow;
            #pragma unroll
            for (int r = 0; r < 4; ++r) {
                const int row = m0 + wr * 128 + mi * 16 + quad * 4 + r;
                C[(size_t)row * N + col] = acc[mi][ni][r];
            }
        }
    }
}

// ---------- MFMA band attention ----------
__global__ __launch_bounds__(256) void attn_mfma_kernel(
    const unsigned short* __restrict__ QKV, unsigned short* __restrict__ O)
{
    constexpr int LDK = 72;   // K/V row stride in bf16 elems (144 B, conflict-free)
    constexpr int LDP = 40;   // P row stride (80 B)
    __shared__ unsigned short Ks[32 * LDK];
    __shared__ unsigned short Vs[32 * LDK];
    __shared__ unsigned short Pl[4][16 * LDP];

    const int t    = threadIdx.x;
    const int wave = t >> 6;
    const int lane = t & 63;
    const int quad = lane >> 4;
    const int c    = lane & 15;
    const int h    = blockIdx.y;
    const int q0   = blockIdx.x * 64;
    const int qw   = q0 + wave * 16;

    const int srow = t >> 3;
    const int scol = (t & 7) * 8;

    const unsigned short* qrow = QKV + (size_t)(qw + c) * 3072 + h * HDIM;
    const s16x8 qf0 = *(const s16x8*)(qrow + quad * 8);
    const s16x8 qf1 = *(const s16x8*)(qrow + 32 + quad * 8);

    float m = -1e30f, lsum = 0.0f;
    f32x4 oacc[4] = {};
    unsigned short* pb = &Pl[wave][0];

    for (int kb = 0; kb < 10; ++kb) {
        const int kstart = q0 - HALFW + kb * 32;
        __syncthreads();
        {
            const int kc = min(max(kstart + srow, 0), SEQ - 1);
            const unsigned short* kr = QKV + (size_t)kc * 3072 + DMODEL + h * HDIM + scol;
            const uint4 kvv = *(const uint4*)kr;
            const uint4 vvv = *(const uint4*)(kr + DMODEL);
            *(uint4*)(Ks + srow * LDK + scol) = kvv;
            *(uint4*)(Vs + srow * LDK + scol) = vvv;
        }
        __syncthreads();

        if (kstart > qw + 15 + HALFW || kstart + 31 < qw - HALFW ||
            kstart + 31 < 0 || kstart >= SEQ)
            continue;

        f32x4 st0 = {0.f, 0.f, 0.f, 0.f}, st1 = {0.f, 0.f, 0.f, 0.f};
        {
            const s16x8 ka00 = *(const s16x8*)(Ks + c * LDK + quad * 8);
            const s16x8 ka01 = *(const s16x8*)(Ks + c * LDK + 32 + quad * 8);
            const s16x8 ka10 = *(const s16x8*)(Ks + (16 + c) * LDK + quad * 8);
            const s16x8 ka11 = *(const s16x8*)(Ks + (16 + c) * LDK + 32 + quad * 8);
            st0 = __builtin_amdgcn_mfma_f32_16x16x32_bf16(ka00, qf0, st0, 0, 0, 0);
            st0 = __builtin_amdgcn_mfma_f32_16x16x32_bf16(ka01, qf1, st0, 0, 0, 0);
            st1 = __builtin_amdgcn_mfma_f32_16x16x32_bf16(ka10, qf0, st1, 0, 0, 0);
            st1 = __builtin_amdgcn_mfma_f32_16x16x32_bf16(ka11, qf1, st1, 0, 0, 0);
        }

        float sv[8];
        #pragma unroll
        for (int j = 0; j < 8; ++j) {
            const int half = j >> 2, r = j & 3;
            const int key = kstart + half * 16 + quad * 4 + r;
            const int d = key - (qw + c);
            const bool valid = (key >= 0) && (key < SEQ) && (d <= HALFW) && (d >= -HALFW);
            const float s = (half ? st1[r] : st0[r]) * 0.125f;
            sv[j] = valid ? s : -1e30f;
        }
        float tmax = sv[0];
        #pragma unroll
        for (int j = 1; j < 8; ++j) tmax = fmaxf(tmax, sv[j]);
        tmax = fmaxf(tmax, __shfl_xor(tmax, 16));
        tmax = fmaxf(tmax, __shfl_xor(tmax, 32));
        const float mnew = fmaxf(m, tmax);
        const float alpha = __expf(m - mnew);
        m = mnew;

        float p[8], psum = 0.0f;
        #pragma unroll
        for (int j = 0; j < 8; ++j) {
            p[j] = (sv[j] > -1e29f) ? __expf(sv[j] - mnew) : 0.0f;
            psum += p[j];
        }
        psum += __shfl_xor(psum, 16);
        psum += __shfl_xor(psum, 32);
        lsum = lsum * alpha + psum;

        #pragma unroll
        for (int j = 0; j < 8; ++j) {
            const int half = j >> 2, r = j & 3;
            pb[c * LDP + half * 16 + quad * 4 + r] = (unsigned short)bf16_rne(p[j]);
        }

        #pragma unroll
        for (int r = 0; r < 4; ++r) {
            const float ar = __shfl(alpha, quad * 4 + r);
            oacc[0][r] *= ar; oacc[1][r] *= ar; oacc[2][r] *= ar; oacc[3][r] *= ar;
        }

        asm volatile("" ::: "memory");
        const s16x8 pa = *(const s16x8*)(pb + c * LDP + quad * 8);

        #pragma unroll
        for (int dt = 0; dt < 4; ++dt) {
            s16x8 vb;
            #pragma unroll
            for (int i = 0; i < 8; ++i)
                vb[i] = (short)Vs[(quad * 8 + i) * LDK + dt * 16 + c];
            oacc[dt] = __builtin_amdgcn_mfma_f32_16x16x32_bf16(pa, vb, oacc[dt], 0, 0, 0);
        }
    }

    #pragma unroll
    for (int r = 0; r < 4; ++r) {
        const float li = 1.0f / __shfl(lsum, quad * 4 + r);
        unsigned short* op = O + (size_t)(qw + quad * 4 + r) * DMODEL + h * HDIM + c;
        op[0]  = (unsigned short)bf16_rne(oacc[0][r] * li);
        op[16] = (unsigned short)bf16_rne(oacc[1][r] * li);
        op[32] = (unsigned short)bf16_rne(oacc[2][r] * li);
        op[48] = (unsigned short)bf16_rne(oacc[3][r] * li);
    }
}

// ---------- launch ----------
extern "C" void kernel_launch(void* const* d_in, const int* in_sizes, int n_in,
                              void* d_out, int out_size, void* d_ws, size_t ws_size,
                              hipStream_t stream)
{
    const int*   ids  = (const int*)d_in[0];
    const float* emb  = (const float*)d_in[1];
    const float* pos  = (const float*)d_in[2];
    const float* wq   = (const float*)d_in[3];
    const float* bq   = (const float*)d_in[4];
    const float* wk   = (const float*)d_in[5];
    const float* bk   = (const float*)d_in[6];
    const float* wv   = (const float*)d_in[7];
    const float* bv   = (const float*)d_in[8];
    const float* wo   = (const float*)d_in[9];
    const float* bo   = (const float*)d_in[10];
    const float* w1   = (const float*)d_in[11];
    const float* b1   = (const float*)d_in[12];
    const float* w2   = (const float*)d_in[13];
    const float* b2   = (const float*)d_in[14];
    const float* ln1g = (const float*)d_in[15];
    const float* ln1b = (const float*)d_in[16];
    const float* ln2g = (const float*)d_in[17];
    const float* ln2b = (const float*)d_in[18];
    const float* outg = (const float*)d_in[19];
    const float* outb = (const float*)d_in[20];

    const size_t SD = (size_t)SEQ * DMODEL;       // 2M
    char* ws = (char*)d_ws;
    float*          x     = (float*)ws;           ws += SD * 4;                       // 8 MB
    unsigned short* qkvb  = (unsigned short*)ws;  ws += (size_t)SEQ * 3 * DMODEL * 2; // 12.6 MB
    unsigned short* hb    = (unsigned short*)ws;  ws += SD * 2;                       // 4 MB
    unsigned short* ob    = (unsigned short*)ws;  ws += SD * 2;                       // 4 MB
    unsigned short* mid   = (unsigned short*)ws;  ws += (size_t)SEQ * 4 * DMODEL * 2; // 16.8 MB
    unsigned short* embT  = (unsigned short*)ws;  ws += (size_t)VOCAB * DMODEL * 2;   // 65.5 MB
    unsigned short* wT    = (unsigned short*)ws;  ws += (size_t)4 * DMODEL * DMODEL * 2; // 8.4 MB
    float*          bias3 = (float*)ws;           ws += 3 * DMODEL * 4;

    const size_t DD  = (size_t)DMODEL * DMODEL;
    const size_t DD4 = (size_t)DMODEL * 4 * DMODEL;

    // emb f32 -> bf16 (layout [V,K] is already the BT layout for logits)
    convert_bf16_kernel<<<(VOCAB * DMODEL) / (256 * 8), 256, 0, stream>>>(emb, embT);

    embed_kernel<<<SEQ, 256, 0, stream>>>(ids, emb, pos, x);

    for (int l = 0; l < NLAYER; ++l) {
        ln_bf16_kernel<<<SEQ, 256, 0, stream>>>(x, ln1g + l * DMODEL, ln1b + l * DMODEL, hb);

        // QKV fused: Wt = [wq^T ; wk^T ; wv^T]  (3072 x 1024), bf16 output
        transpose_bf16_kernel<<<dim3(16, 16), 256, 0, stream>>>(wq + l * DD, wT,          DMODEL, DMODEL);
        transpose_bf16_kernel<<<dim3(16, 16), 256, 0, stream>>>(wk + l * DD, wT + DD,     DMODEL, DMODEL);
        transpose_bf16_kernel<<<dim3(16, 16), 256, 0, stream>>>(wv + l * DD, wT + 2 * DD, DMODEL, DMODEL);
        pack3_kernel<<<12, 256, 0, stream>>>(bq + l * DMODEL, bk + l * DMODEL, bv + l * DMODEL, bias3);

        gemm_bf16<128, 0, 1, 1><<<dim3(16, 24), 256, 0, stream>>>(
            hb, wT, bias3, nullptr, nullptr, qkvb, SEQ, 3 * DMODEL, DMODEL);

        attn_mfma_kernel<<<dim3(SEQ / 64, NHEAD), 256, 0, stream>>>(qkvb, ob);

        transpose_bf16_kernel<<<dim3(16, 16), 256, 0, stream>>>(wo + l * DD, wT, DMODEL, DMODEL);
        gemm_bf16<64, 0, 0, 0><<<dim3(32, 8), 256, 0, stream>>>(
            ob, wT, bo + l * DMODEL, x, x, nullptr, SEQ, DMODEL, DMODEL);

        ln_bf16_kernel<<<SEQ, 256, 0, stream>>>(x, ln2g + l * DMODEL, ln2b + l * DMODEL, hb);

        transpose_bf16_kernel<<<dim3(16, 64), 256, 0, stream>>>(w1 + l * DD4, wT, DMODEL, 4 * DMODEL);
        gemm_bf16<128, 1, 1, 1><<<dim3(16, 32), 256, 0, stream>>>(
            hb, wT, b1 + l * 4 * DMODEL, nullptr, nullptr, mid, SEQ, 4 * DMODEL, DMODEL);

        transpose_bf16_kernel<<<dim3(64, 16), 256, 0, stream>>>(w2 + l * DD4, wT, 4 * DMODEL, DMODEL);
        gemm_bf16<64, 0, 0, 0><<<dim3(32, 8), 256, 0, stream>>>(
            mid, wT, b2 + l * DMODEL, x, x, nullptr, SEQ, DMODEL, 4 * DMODEL);
    }

    ln_bf16_kernel<<<SEQ, 256, 0, stream>>>(x, outg, outb, hb);

    // logits = hb @ embT^T -> d_out f32, 256^2 pipelined GEMM
    gemm256_bf16<<<dim3(SEQ / 256, VOCAB / 256), 512, 0, stream>>>(
        hb, embT, (float*)d_out, SEQ, VOCAB, DMODEL);
}